// Round 5
// baseline (349.966 us; speedup 1.0000x reference)
//
#include <hip/hip_runtime.h>

#define B_ 16
#define S_ 20
#define L_ 64
#define T_ 1280
#define H_ 768
#define NITEMS 50000
#define TEMP 0.05f
#define EPSN 1e-8f

#define BN2 32
#define NKT 24                              // 768/32 k-steps
#define NCHUNK ((NITEMS + BN2 - 1) / BN2)   // 1563 blocks

typedef __attribute__((ext_vector_type(8))) short short8;
typedef __attribute__((ext_vector_type(4))) float f32x4;

// float -> bf16 (round-to-nearest-even)
__device__ __forceinline__ unsigned short f2bf(float f) {
    unsigned int u = __float_as_uint(f);
    u = u + 0x7FFFu + ((u >> 16) & 1u);
    return (unsigned short)(u >> 16);
}
__device__ __forceinline__ unsigned int pack2bf(float a, float b) {
    return (unsigned int)f2bf(a) | ((unsigned int)f2bf(b) << 16);
}

// ---------------------------------------------------------------------------
// Kernel 1: per-(b,s) nan-mean pool, normalize, fold 1/(pn*TEMP), write bf16.
// LINEAR row-major output (gemm now reads A via direct global 16B loads —
// no LDS staging of A, so no swizzle needed).
// ---------------------------------------------------------------------------
__global__ __launch_bounds__(384) void pool_kernel(const float* __restrict__ hidden,
                                                   const int* __restrict__ pos,
                                                   unsigned short* __restrict__ A,
                                                   int* __restrict__ valid) {
    const int row = blockIdx.x;  // 0..319
    const int b = row / S_, s = row % S_;
    const int tid = threadIdx.x;  // 0..383; thread owns cols 2*tid, 2*tid+1

    __shared__ float wgt[L_];
    __shared__ int cntS;
    __shared__ float red[6];

    const int* pbase = pos + b * T_ + s * L_;
    if (tid < L_) {  // exactly wave 0
        const int match = (pbase[tid] == s + 1) ? 1 : 0;
        unsigned long long bal = __ballot(match);
        wgt[tid] = match ? 1.0f : 0.0f;
        if (tid == 0) cntS = (int)__popcll(bal);
    }
    __syncthreads();

    const int cnt = cntS;
    const float inv = 1.0f / (float)(cnt > 0 ? cnt : 1);
    const float* hbase = hidden + ((size_t)b * T_ + (size_t)s * L_) * H_ + tid * 2;

    float a0 = 0.f, a1 = 0.f;
#pragma unroll 8
    for (int t = 0; t < L_; ++t) {
        const float w = wgt[t];
        const float2 v = *reinterpret_cast<const float2*>(hbase + (size_t)t * H_);
        a0 += w * v.x; a1 += w * v.y;
    }
    a0 *= inv; a1 *= inv;

    // sum of squares over 768 cols (6 waves)
    float ss = a0 * a0 + a1 * a1;
#pragma unroll
    for (int off = 32; off; off >>= 1) ss += __shfl_xor(ss, off, 64);
    const int wave = tid >> 6, lane = tid & 63;
    if (lane == 0) red[wave] = ss;
    __syncthreads();
    const float tot = red[0] + red[1] + red[2] + red[3] + red[4] + red[5];
    const float scale = 1.0f / (fmaxf(sqrtf(tot), EPSN) * TEMP);

    *reinterpret_cast<unsigned int*>(A + (size_t)row * H_ + tid * 2) =
        pack2bf(a0 * scale, a1 * scale);
    if (tid == 0) valid[row] = (cnt > 0) ? 1 : 0;
}

// ---------------------------------------------------------------------------
// Kernel 2: persistent-B GEMM. R0-R4 post-mortem: all schedules were limited
// by B's per-iteration cold 128B k-slice scatter (0.5-0.9 TB/s effective).
// Restructure so each emb row enters the CU exactly ONCE, contiguously:
//  - block owns BN2=32 items x ALL 320 sessions (M fits one block).
//  - stage phase: read 32 full rows fp32 coalesced (96 KB = the block's only
//    HBM traffic), compute en (fp32 exact), cvt->bf16, slot-swizzled LDS.
//  - ONE __syncthreads. K-loop: ZERO barriers, ZERO manual waitcnt.
//  - A-fragments stream global->regs (480 KB total, L2-hot everywhere; wave
//    reads 16 rows x 64B segments = coalesced), 2-step reg double-buffer:
//    in-order vmcnt retirement waits only the current 5 frags.
//  - LDS 48.4 KB -> 3 blocks/CU (3 waves/SIMD): one block's HBM staging
//    overlaps two others' K-loops; HBM streams continuously.
// B-read swizzle: 16B-slot phys = (slot&~7) | ((slot&7) ^ (row&7)) — row
// stride 1536B = 0 mod 32 banks, so the XOR spreads the 8 low-lanes across
// all 8 slot-bank-groups (2-way residual = free).
// ---------------------------------------------------------------------------
__global__ __launch_bounds__(256, 3) void gemm_kernel(const float* __restrict__ emb,
                                                      const unsigned short* __restrict__ A,
                                                      const int* __restrict__ valid,
                                                      float* __restrict__ out) {
    const int n0 = blockIdx.x * BN2;
    const int tid = threadIdx.x;
    const int wave = tid >> 6, lane = tid & 63, quad = lane >> 4, lq = lane & 15;

    __shared__ alignas(16) short Bs[BN2 * H_];  // 48 KB bf16, slot-swizzled
    __shared__ float sEn[BN2];
    __shared__ int sMask[B_];

    // per-session validity bitmask (20 bits)
    if (tid < B_) {
        int m = 0;
        for (int s = 0; s < S_; ++s) m |= (valid[tid * S_ + s] ? 1 : 0) << s;
        sMask[tid] = m;
    }

    // ---- stage B: wave stages rows wave*8 .. wave*8+7 (full rows, once) ----
    {
        const int lrB = wave * 8;
        const float* src[8];
#pragma unroll
        for (int rr = 0; rr < 8; ++rr) {
            int gr = n0 + lrB + rr;
            if (gr > NITEMS - 1) gr = NITEMS - 1;  // clamp: computed, never stored
            src[rr] = emb + (size_t)gr * H_ + lane * 4;
        }
        // issue all 24 loads first (24 KB/wave in flight -> HBM saturating)
        f32x4 v[8][3];
#pragma unroll
        for (int rr = 0; rr < 8; ++rr)
#pragma unroll
            for (int s = 0; s < 3; ++s)
                v[rr][s] = *reinterpret_cast<const f32x4*>(src[rr] + s * 256);
#pragma unroll
        for (int rr = 0; rr < 8; ++rr) {
            const int r = lrB + rr;
            float ss = 0.f;
#pragma unroll
            for (int s = 0; s < 3; ++s)
                ss += v[rr][s][0] * v[rr][s][0] + v[rr][s][1] * v[rr][s][1] +
                      v[rr][s][2] * v[rr][s][2] + v[rr][s][3] * v[rr][s][3];
#pragma unroll
            for (int off = 32; off; off >>= 1) ss += __shfl_xor(ss, off, 64);
            if (lane == 0) sEn[r] = fmaxf(sqrtf(ss), EPSN);
            // cvt + swizzled write: lane's 4 floats = half of 16B-slot
            // slot = s*32 + (lane>>1), half = lane&1
#pragma unroll
            for (int s = 0; s < 3; ++s) {
                const int slot = s * 32 + (lane >> 1);
                const int phys = (slot & ~7) | ((slot & 7) ^ (r & 7));
                unsigned int p0 = pack2bf(v[rr][s][0], v[rr][s][1]);
                unsigned int p1 = pack2bf(v[rr][s][2], v[rr][s][3]);
                uint2* dst = reinterpret_cast<uint2*>(
                    (char*)(&Bs[0]) + r * (H_ * 2) + phys * 16 + (lane & 1) * 8);
                *dst = make_uint2(p0, p1);
            }
        }
    }
    __syncthreads();  // the ONLY barrier

    // ---- K-loop: stationary LDS B, A direct global->regs ----
    f32x4 acc[5][2];
#pragma unroll
    for (int a = 0; a < 5; ++a)
#pragma unroll
        for (int b = 0; b < 2; ++b) acc[a][b] = (f32x4)0.f;

    const unsigned short* aBase[5];
#pragma unroll
    for (int mf = 0; mf < 5; ++mf)
        aBase[mf] = A + (size_t)(wave * 80 + mf * 16 + lq) * H_ + quad * 8;

#define LOADA(dst, kt)                                                           \
    _Pragma("unroll") for (int mf = 0; mf < 5; ++mf)                             \
        dst[mf] = *reinterpret_cast<const short8*>(aBase[mf] + (kt) * 32)

#define BREAD(dst, kt)                                                           \
    _Pragma("unroll") for (int nf = 0; nf < 2; ++nf) {                           \
        const int r_ = nf * 16 + lq;                                             \
        const int slot_ = (kt) * 4 + quad;                                       \
        const int phys_ = (slot_ & ~7) | ((slot_ & 7) ^ (lq & 7));               \
        dst[nf] = *reinterpret_cast<const short8*>((const char*)(&Bs[0]) +       \
                                                   r_ * (H_ * 2) + phys_ * 16);  \
    }

#define MFMAS(af, bf)                                                            \
    _Pragma("unroll") for (int mf = 0; mf < 5; ++mf)                             \
        _Pragma("unroll") for (int nf = 0; nf < 2; ++nf)                         \
            acc[mf][nf] = __builtin_amdgcn_mfma_f32_16x16x32_bf16(               \
                af[mf], bf[nf], acc[mf][nf], 0, 0, 0)

    short8 aA[5], aB[5], bA[2], bB[2];
    LOADA(aA, 0);
    for (int kt = 0; kt < NKT; kt += 2) {
        LOADA(aB, kt + 1);            // prefetch (in flight across aA's MFMAs)
        BREAD(bA, kt);
        MFMAS(aA, bA);
        if (kt + 2 < NKT) LOADA(aA, kt + 2);
        BREAD(bB, kt + 1);
        MFMAS(aB, bB);
    }
#undef LOADA
#undef BREAD
#undef MFMAS

    // epilogue: wave w owns sessions 4w..4w+3 (local rows bl*20..bl*20+19).
    // C/D layout: col = lane&15 (n), row = quad*4+e (m).
#pragma unroll
    for (int nf = 0; nf < 2; ++nf) {
        const int ncol = nf * 16 + lq;
        const int n = n0 + ncol;
        const float inv_en = 1.0f / sEn[ncol];
#pragma unroll
        for (int bl = 0; bl < 4; ++bl) {
            const int bb = wave * 4 + bl;
            const int msk = sMask[bb];
            const int rLo = bl * S_;
            float lm = -__builtin_inff();
            const int mfLo = rLo >> 4;
            const int mfHi = (rLo + S_ - 1) >> 4;
#pragma unroll
            for (int mf = mfLo; mf <= mfHi; ++mf)
#pragma unroll
                for (int e = 0; e < 4; ++e) {
                    const int r = mf * 16 + quad * 4 + e;
                    const unsigned off = (unsigned)(r - rLo);
                    const bool ok = (off < (unsigned)S_) && ((msk >> off) & 1);
                    lm = ok ? fmaxf(lm, acc[mf][nf][e]) : lm;
                }
            lm = fmaxf(lm, __shfl_xor(lm, 16, 64));
            lm = fmaxf(lm, __shfl_xor(lm, 32, 64));
            if (quad == 0 && n < NITEMS)
                out[(size_t)bb * NITEMS + n] = lm * inv_en;
        }
    }
}

extern "C" void kernel_launch(void* const* d_in, const int* in_sizes, int n_in,
                              void* d_out, int out_size, void* d_ws, size_t ws_size,
                              hipStream_t stream) {
    const float* hidden = (const float*)d_in[0];   // [16,1280,768] f32
    const float* emb    = (const float*)d_in[1];   // [50000,768] f32
    const int*   pos    = (const int*)d_in[3];     // [16,1280] i32
    float* out = (float*)d_out;                    // [16,50000] f32

    unsigned short* Abf = (unsigned short*)d_ws;               // 320*768 bf16 (linear)
    int* valid = (int*)((char*)d_ws + (size_t)320 * 768 * 2);  // 320 ints

    pool_kernel<<<dim3(320), dim3(384), 0, stream>>>(hidden, pos, Abf, valid);
    gemm_kernel<<<dim3(NCHUNK), dim3(256), 0, stream>>>(emb, Abf, valid, out);
}